// Round 1
// baseline (481.537 us; speedup 1.0000x reference)
//
#include <hip/hip_runtime.h>
#include <hip/hip_bf16.h>

// Sizes (fixed by the reference)
#define MMH 256      // M == H == F == 256
#define TT 4
#define NSEMN 40
#define HM 65536     // H*M

using short8 = __attribute__((ext_vector_type(8))) short;
using f32x4  = __attribute__((ext_vector_type(4))) float;

__device__ __forceinline__ unsigned short f2bf(float x) {
  union { float f; unsigned int u; } v; v.f = x;
  unsigned int r = v.u + 0x7fffu + ((v.u >> 16) & 1u);   // RNE
  return (unsigned short)(r >> 16);
}

// ---------------------------------------------------------------------------
// 1) pf = relu(parent @ W_parent + b_parent) -> cat[m*768 + h]  (cf0 slice)
__global__ __launch_bounds__(256) void k_parent(
    const float* __restrict__ pf, const float* __restrict__ Wp,
    const float* __restrict__ bp, float* __restrict__ cat) {
  int j = blockIdx.x * 256 + threadIdx.x;   // 0..65535
  float acc = bp[j];
  #pragma unroll 8
  for (int f = 0; f < MMH; ++f) acc += pf[f] * Wp[(size_t)f * HM + j];
  int m = j >> 8, h = j & 255;
  cat[m * 768 + h] = fmaxf(acc, 0.0f);
}

// ---------------------------------------------------------------------------
// 2) child_exists logits (exact f32) + flags init.  One wave per row m.
__global__ __launch_bounds__(64) void k_cel(
    const float* __restrict__ cat, const float* __restrict__ Wex,
    const float* __restrict__ bex, float* __restrict__ cel,
    float* __restrict__ out_ex, int* __restrict__ flags) {
  int m = blockIdx.x, l = threadIdx.x;
  float s = 0.f;
  for (int h = l; h < MMH; h += 64) s += cat[m * 768 + h] * Wex[h];
  #pragma unroll
  for (int off = 32; off > 0; off >>= 1) s += __shfl_down(s, off);
  if (l == 0) { float v = s + bex[0]; cel[m] = v; out_ex[m] = v; }
  if (m == 0 && l == 0) flags[0] = 0;
}

// ---------------------------------------------------------------------------
// Generic small f32 GEMM: C[rows x N2] = op(A[rows x K2] @ B[K2 x N2] + bias)
// 16x16 thread tile; rows and K2 must be multiples of 16; N2 guarded.
__global__ __launch_bounds__(256) void k_gemm16(
    const float* __restrict__ A, int lda, const float* __restrict__ B, int ldb,
    const float* __restrict__ bias, float* __restrict__ C, int ldc,
    int N2, int K2, int relu) {
  __shared__ float As[16][17], Bs[16][17];
  int tx = threadIdx.x, ty = threadIdx.y;
  int row = blockIdx.y * 16 + ty, col = blockIdx.x * 16 + tx;
  float acc = 0.f;
  for (int k0 = 0; k0 < K2; k0 += 16) {
    As[ty][tx] = A[row * lda + k0 + tx];
    Bs[ty][tx] = (col < N2) ? B[(k0 + ty) * ldb + col] : 0.f;
    __syncthreads();
    #pragma unroll
    for (int kk = 0; kk < 16; ++kk) acc += As[ty][kk] * Bs[kk][tx];
    __syncthreads();
  }
  if (col < N2) {
    if (bias) acc += bias[col];
    if (relu) acc = fmaxf(acc, 0.f);
    C[row * ldc + col] = acc;
  }
}

// ---------------------------------------------------------------------------
// 3) edge_exists_logits (exact f32) + has_edge flag.  One wave per (m,n).
__global__ __launch_bounds__(256) void k_edge(
    const float* __restrict__ Xi, const float* __restrict__ Xj,
    const float* __restrict__ bel, const float* __restrict__ Wee,
    const float* __restrict__ bee, const float* __restrict__ cel,
    float* __restrict__ out_eel, int* __restrict__ flags) {
  __shared__ int anyEdge;
  if (threadIdx.x == 0) anyEdge = 0;
  __syncthreads();
  int wv = blockIdx.x * 4 + (threadIdx.x >> 6);    // pair id 0..65535
  int lane = threadIdx.x & 63;
  int m = wv >> 8, n = wv & 255;
  float4 a = ((const float4*)(Xi + m * MMH))[lane];
  float4 b = ((const float4*)(Xj + n * MMH))[lane];
  float4 c = ((const float4*)bel)[lane];
  float e0 = fmaxf(a.x + b.x + c.x, 0.f);
  float e1 = fmaxf(a.y + b.y + c.y, 0.f);
  float e2 = fmaxf(a.z + b.z + c.z, 0.f);
  float e3 = fmaxf(a.w + b.w + c.w, 0.f);
  float s[TT];
  #pragma unroll
  for (int t = 0; t < TT; ++t) {
    float4 w = ((const float4*)(Wee + t * MMH))[lane];
    s[t] = e0 * w.x + e1 * w.y + e2 * w.z + e3 * w.w;
  }
  #pragma unroll
  for (int off = 1; off < 64; off <<= 1) {
    #pragma unroll
    for (int t = 0; t < TT; ++t) s[t] += __shfl_xor(s[t], off);
  }
  bool edge = false;
  if (lane == 0) {
    float4 r;
    r.x = s[0] + bee[0]; r.y = s[1] + bee[1];
    r.z = s[2] + bee[2]; r.w = s[3] + bee[3];
    ((float4*)out_eel)[wv] = r;
    bool nm = cel[m] > 0.f, nn = cel[n] > 0.f;
    edge = nm && nn && (r.x > 0.f || r.y > 0.f || r.z > 0.f || r.w > 0.f);
  }
  if (edge) atomicOr(&anyEdge, 1);
  __syncthreads();
  if (threadIdx.x == 0 && anyEdge) atomicOr(flags, 1);
}

// ---------------------------------------------------------------------------
__global__ __launch_bounds__(256) void k_zero(float* __restrict__ p) {
  p[blockIdx.x * 256 + threadIdx.x] = 0.f;
}

// ---------------------------------------------------------------------------
// 4) THE big fused kernel, per message-passing iteration:
//    E[m,n,k] = sum_h relu(Xi[m,h]+Xj[n,h]+b_el[h]) * We[h,k]   (bf16 MFMA)
//    pre = E + Ai[m,k] + Bj[n,k] + eel[m,n,t]*Wt[t,k] + b_ne[k]
//    newcf[m,k] = max(0, max over unmasked (n,t) of pre)  via atomicMax
// Block tile: 4 m x 16 n = 64 pairs, full k=256; 4 waves, wave w owns k-cols
// [w*64, w*64+64).  16x16x32 bf16 MFMA; K-loop of 8 steps of 32 h.
#define ELP 56    // LDS pitch in ushorts (112 B: 16B-aligned, low conflicts)
__global__ __launch_bounds__(256) void k_iter(
    const float* __restrict__ Xi, const float* __restrict__ Xj,
    const float* __restrict__ bel, const float* __restrict__ We,
    const float* __restrict__ Ai, const float* __restrict__ Bj,
    const float* __restrict__ Wt, const float* __restrict__ bne,
    const float* __restrict__ eel, const float* __restrict__ cel,
    float* __restrict__ newcf) {
  __shared__ unsigned short ELs[64 * ELP];     // 64 pairs x 32 h (bf16)
  __shared__ unsigned short WesT[256 * ELP];   // 256 k x 32 h (bf16, transposed)
  int tid = threadIdx.x;
  int w = tid >> 6, lane = tid & 63;
  int m0 = (blockIdx.x >> 4) * 4, n0 = (blockIdx.x & 15) * 16;
  f32x4 acc[4][4] = {};

  for (int h0 = 0; h0 < MMH; h0 += 32) {
    // stage EL tile: row = (ml*16+nl), 8 h's per thread, bf16
    {
      int row = tid & 63, g = tid >> 6;
      int mI = m0 + (row >> 4), nI = n0 + (row & 15);
      const float* xip = Xi + mI * MMH + h0 + g * 8;
      const float* xjp = Xj + nI * MMH + h0 + g * 8;
      const float* bp  = bel + h0 + g * 8;
      short8 v;
      #pragma unroll
      for (int j = 0; j < 8; ++j)
        v[j] = (short)f2bf(fmaxf(xip[j] + xjp[j] + bp[j], 0.f));
      *(short8*)&ELs[row * ELP + g * 8] = v;
    }
    // stage We tile transposed: thread tid handles output-col k=tid
    {
      const float* wp = We + (size_t)h0 * MMH + tid;
      #pragma unroll
      for (int hh = 0; hh < 32; ++hh)
        WesT[tid * ELP + hh] = f2bf(wp[(size_t)hh * MMH]);
    }
    __syncthreads();
    short8 af[4], bf[4];
    #pragma unroll
    for (int rt = 0; rt < 4; ++rt)
      af[rt] = *(const short8*)&ELs[(rt * 16 + (lane & 15)) * ELP + (lane >> 4) * 8];
    #pragma unroll
    for (int ct = 0; ct < 4; ++ct)
      bf[ct] = *(const short8*)&WesT[(w * 64 + ct * 16 + (lane & 15)) * ELP + (lane >> 4) * 8];
    #pragma unroll
    for (int rt = 0; rt < 4; ++rt)
      #pragma unroll
      for (int ct = 0; ct < 4; ++ct)
        acc[rt][ct] = __builtin_amdgcn_mfma_f32_16x16x32_bf16(af[rt], bf[ct], acc[rt][ct], 0, 0, 0);
    __syncthreads();
  }

  // Epilogue: D elem (row = grp*4+r, col = lane&15) of each 16x16 tile.
  int col = lane & 15, grp = lane >> 4;
  #pragma unroll
  for (int rt = 0; rt < 4; ++rt) {
    int m = m0 + rt;
    bool nem = cel[m] > 0.f;
    float4 e4[4]; bool nen[4];
    #pragma unroll
    for (int r = 0; r < 4; ++r) {
      int n = n0 + grp * 4 + r;
      e4[r] = ((const float4*)eel)[m * 256 + n];
      nen[r] = cel[n] > 0.f;
    }
    #pragma unroll
    for (int ct = 0; ct < 4; ++ct) {
      int k = w * 64 + ct * 16 + col;
      float basek = Ai[m * MMH + k] + bne[k];
      float wt0 = Wt[0 * MMH + k], wt1 = Wt[1 * MMH + k];
      float wt2 = Wt[2 * MMH + k], wt3 = Wt[3 * MMH + k];
      float vmax = 0.f;
      #pragma unroll
      for (int r = 0; r < 4; ++r) {
        int n = n0 + grp * 4 + r;
        float base = acc[rt][ct][r] + basek + Bj[n * MMH + k];
        if (nem && nen[r]) {
          if (e4[r].x > 0.f) vmax = fmaxf(vmax, base + e4[r].x * wt0);
          if (e4[r].y > 0.f) vmax = fmaxf(vmax, base + e4[r].y * wt1);
          if (e4[r].z > 0.f) vmax = fmaxf(vmax, base + e4[r].z * wt2);
          if (e4[r].w > 0.f) vmax = fmaxf(vmax, base + e4[r].w * wt3);
        }
      }
      vmax = fmaxf(vmax, __shfl_xor(vmax, 16));
      vmax = fmaxf(vmax, __shfl_xor(vmax, 32));
      if (grp == 0 && vmax > 0.f)
        atomicMax((unsigned int*)&newcf[m * MMH + k], __float_as_uint(vmax));
    }
  }
}

// ---------------------------------------------------------------------------
// 5) cf_{i+1} = has_edge ? newcf : cf_i ; also re-zero newcf for next iter.
__global__ __launch_bounds__(256) void k_select(
    const int* __restrict__ flags, float* __restrict__ newcf,
    float* __restrict__ cat, int iter) {
  int idx = blockIdx.x * 256 + threadIdx.x;
  int m = idx >> 8, k = idx & 255;
  float prev = cat[m * 768 + iter * 256 + k];
  float v = flags[0] ? newcf[idx] : prev;
  cat[m * 768 + (iter + 1) * 256 + k] = v;
  newcf[idx] = 0.f;
}

// ---------------------------------------------------------------------------
extern "C" void kernel_launch(void* const* d_in, const int* in_sizes, int n_in,
                              void* d_out, int out_size, void* d_ws, size_t ws_size,
                              hipStream_t stream) {
  const float* pf   = (const float*)d_in[0];
  const float* Wp   = (const float*)d_in[1];
  const float* bp   = (const float*)d_in[2];
  const float* Wex  = (const float*)d_in[3];
  const float* bex  = (const float*)d_in[4];
  const float* Wel  = (const float*)d_in[5];
  const float* bel  = (const float*)d_in[6];
  const float* Wee  = (const float*)d_in[7];
  const float* bee  = (const float*)d_in[8];
  const float* Wne  = (const float*)d_in[9];
  const float* bne  = (const float*)d_in[10];
  const float* Wch  = (const float*)d_in[11];
  const float* bch  = (const float*)d_in[12];
  const float* Wsem = (const float*)d_in[13];
  const float* bsem = (const float*)d_in[14];
  const float* Wch2 = (const float*)d_in[15];
  const float* bch2 = (const float*)d_in[16];
  float* out = (float*)d_out;
  float* ws  = (float*)d_ws;

  // workspace layout (floats) — ~2.4 MB total
  float* cat    = ws;               // 256 x 768 (cf0|cf1|cf2 concatenated)
  float* Xi     = ws + 196608;      // 256 x 256
  float* Xj     = Xi + 65536;
  float* Ai     = Xj + 65536;
  float* Bj     = Ai + 65536;
  float* newcf  = Bj + 65536;
  float* hidden = newcf + 65536;
  float* cel    = hidden + 65536;   // 256
  int*   flags  = (int*)(cel + 256);

  float* out_cf  = out;             // (1,256,256)
  float* out_sem = out + 65536;     // (1,256,40)
  float* out_ex  = out + 75776;     // (1,256,1)
  float* out_eel = out + 76032;     // (1,256,256,4)

  dim3 b16(16, 16);
  k_parent<<<256, 256, 0, stream>>>(pf, Wp, bp, cat);
  k_cel<<<256, 64, 0, stream>>>(cat, Wex, bex, cel, out_ex, flags);
  k_gemm16<<<dim3(16, 16), b16, 0, stream>>>(cat, 768, Wel, 256, nullptr, Xi, 256, 256, 256, 0);
  k_gemm16<<<dim3(16, 16), b16, 0, stream>>>(cat, 768, Wel + 65536, 256, nullptr, Xj, 256, 256, 256, 0);
  k_edge<<<16384, 256, 0, stream>>>(Xi, Xj, bel, Wee, bee, cel, out_eel, flags);
  k_zero<<<256, 256, 0, stream>>>(newcf);
  for (int i = 0; i < 2; ++i) {
    const float* cfi = cat + i * 256;                         // lda = 768
    const float* Wi  = Wne + (size_t)(i * 772 + 0)   * 256;
    const float* Wj  = Wne + (size_t)(i * 772 + 256) * 256;
    const float* We  = Wne + (size_t)(i * 772 + 512) * 256;
    const float* Wt  = Wne + (size_t)(i * 772 + 768) * 256;
    const float* bnei = bne + i * 256;
    k_gemm16<<<dim3(16, 16), b16, 0, stream>>>(cfi, 768, Wi, 256, nullptr, Ai, 256, 256, 256, 0);
    k_gemm16<<<dim3(16, 16), b16, 0, stream>>>(cfi, 768, Wj, 256, nullptr, Bj, 256, 256, 256, 0);
    k_iter<<<1024, 256, 0, stream>>>(Xi, Xj, bel, We, Ai, Bj, Wt, bnei, out_eel, cel, newcf);
    k_select<<<256, 256, 0, stream>>>(flags, newcf, cat, i);
  }
  k_gemm16<<<dim3(16, 16), b16, 0, stream>>>(cat, 768, Wch, 256, bch, hidden, 256, 256, 768, 1);
  k_gemm16<<<dim3(3, 16), b16, 0, stream>>>(hidden, 256, Wsem, 40, bsem, out_sem, 40, NSEMN, 256, 0);
  k_gemm16<<<dim3(16, 16), b16, 0, stream>>>(hidden, 256, Wch2, 256, bch2, out_cf, 256, 256, 256, 1);
}

// Round 9
// 350.182 us; speedup vs baseline: 1.3751x; 1.3751x over previous
//
#include <hip/hip_runtime.h>
#include <hip/hip_bf16.h>

// Sizes (fixed by the reference)
#define MMH 256      // M == H == F == 256
#define TT 4
#define NSEMN 40
#define HM 65536     // H*M

using short8 = __attribute__((ext_vector_type(8))) short;
using f32x4  = __attribute__((ext_vector_type(4))) float;

__device__ __forceinline__ unsigned short f2bf(float x) {
  union { float f; unsigned int u; } v; v.f = x;
  unsigned int r = v.u + 0x7fffu + ((v.u >> 16) & 1u);   // RNE
  return (unsigned short)(r >> 16);
}

// ---------------------------------------------------------------------------
// 1) pf = relu(parent @ W_parent + b_parent) -> cat[m*768 + h]  (cf0 slice)
__global__ __launch_bounds__(256) void k_parent(
    const float* __restrict__ pf, const float* __restrict__ Wp,
    const float* __restrict__ bp, float* __restrict__ cat) {
  int j = blockIdx.x * 256 + threadIdx.x;   // 0..65535
  float acc = bp[j];
  #pragma unroll 8
  for (int f = 0; f < MMH; ++f) acc += pf[f] * Wp[(size_t)f * HM + j];
  int m = j >> 8, h = j & 255;
  cat[m * 768 + h] = fmaxf(acc, 0.0f);
}

// ---------------------------------------------------------------------------
// 2) child_exists logits (exact f32) + flags init.  One wave per row m.
__global__ __launch_bounds__(64) void k_cel(
    const float* __restrict__ cat, const float* __restrict__ Wex,
    const float* __restrict__ bex, float* __restrict__ cel,
    float* __restrict__ out_ex, int* __restrict__ flags) {
  int m = blockIdx.x, l = threadIdx.x;
  float s = 0.f;
  for (int h = l; h < MMH; h += 64) s += cat[m * 768 + h] * Wex[h];
  #pragma unroll
  for (int off = 32; off > 0; off >>= 1) s += __shfl_down(s, off);
  if (l == 0) { float v = s + bex[0]; cel[m] = v; out_ex[m] = v; }
  if (m == 0 && l == 0) flags[0] = 0;
}

// ---------------------------------------------------------------------------
// Small f32 GEMM, dual-output via gridDim.z: z picks (B,C) pair.
// ldb restored as a parameter (round-5 bug: hard-coded 256 broke W_sem ldb=40).
__global__ __launch_bounds__(256) void k_gemm16(
    const float* __restrict__ A, int lda,
    const float* __restrict__ B0, const float* __restrict__ B1, int ldb,
    const float* __restrict__ bias,
    float* __restrict__ C0, float* __restrict__ C1, int ldc,
    int N2, int K2, int relu) {
  const float* B = blockIdx.z ? B1 : B0;
  float*       C = blockIdx.z ? C1 : C0;
  __shared__ float As[16][17], Bs[16][17];
  int tx = threadIdx.x, ty = threadIdx.y;
  int row = blockIdx.y * 16 + ty, col = blockIdx.x * 16 + tx;
  float acc = 0.f;
  for (int k0 = 0; k0 < K2; k0 += 16) {
    As[ty][tx] = A[row * lda + k0 + tx];
    Bs[ty][tx] = (col < N2) ? B[(k0 + ty) * ldb + col] : 0.f;
    __syncthreads();
    #pragma unroll
    for (int kk = 0; kk < 16; ++kk) acc += As[ty][kk] * Bs[kk][tx];
    __syncthreads();
  }
  if (col < N2) {
    if (bias) acc += bias[col];
    if (relu) acc = fmaxf(acc, 0.f);
    C[row * ldc + col] = acc;
  }
}

// ---------------------------------------------------------------------------
// 2.5) Prep: We (f32 [h][k]) -> WeTb bf16 tiled [(h/32)][k][h%32] per iter,
//      plus Wee transposed to float4-per-h table.
__global__ __launch_bounds__(256) void k_tr(
    const float* __restrict__ Wne, const float* __restrict__ Wee,
    unsigned short* __restrict__ WeTb, float* __restrict__ Wee4g) {
  int i = blockIdx.z;
  const float* We = Wne + (size_t)(i * 772 + 512) * 256;
  unsigned short* out = WeTb + i * 65536;
  __shared__ float t[32][33];             // t[h_local][k_local]
  int tx = threadIdx.x, ty = threadIdx.y; // block (32,8)
  int h0 = blockIdx.y * 32, k0 = blockIdx.x * 32;
  #pragma unroll
  for (int j = 0; j < 4; ++j)
    t[ty + j * 8][tx] = We[(size_t)(h0 + ty + j * 8) * 256 + k0 + tx];
  __syncthreads();
  #pragma unroll
  for (int j = 0; j < 4; ++j) {
    int kl = ty + j * 8;
    out[((h0 >> 5) * 256 + k0 + kl) * 32 + tx] = f2bf(t[tx][kl]);
  }
  if (blockIdx.x == 0 && blockIdx.y == 0 && i == 0) {
    int t2 = ty * 32 + tx;
    float4 w;
    w.x = Wee[t2]; w.y = Wee[256 + t2]; w.z = Wee[512 + t2]; w.w = Wee[768 + t2];
    ((float4*)Wee4g)[t2] = w;
  }
}

// ---------------------------------------------------------------------------
// 3) edge_exists_logits (exact f32, thread-per-pair) + has_edge flag.
#define XP 260
__global__ __launch_bounds__(256) void k_edge(
    const float* __restrict__ Xi, const float* __restrict__ Xj,
    const float* __restrict__ bel, const float* __restrict__ Wee4g,
    const float* __restrict__ bee, const float* __restrict__ cel,
    float* __restrict__ out_eel, int* __restrict__ flags) {
  __shared__ float XiS[16 * XP], XjS[16 * XP];
  __shared__ int anyEdge;
  int tid = threadIdx.x;
  int m0 = (blockIdx.x >> 4) * 16, n0 = (blockIdx.x & 15) * 16;
  if (tid == 0) anyEdge = 0;
  #pragma unroll
  for (int j = 0; j < 4; ++j) {
    int c = tid + 256 * j;                 // 1024 chunks of 16B
    int row = c >> 6, c4 = (c & 63) * 4;
    float4 v = *(const float4*)(Xi + (m0 + row) * 256 + c4);
    float4 b = *(const float4*)(bel + c4);
    v.x += b.x; v.y += b.y; v.z += b.z; v.w += b.w;   // fold bel into Xi tile
    *(float4*)&XiS[row * XP + c4] = v;
    *(float4*)&XjS[row * XP + c4] = *(const float4*)(Xj + (n0 + row) * 256 + c4);
  }
  __syncthreads();
  int tm = tid >> 4, tn = tid & 15;
  const float* xr = &XiS[tm * XP];
  const float* yr = &XjS[tn * XP];
  float4 s = {0.f, 0.f, 0.f, 0.f};
  for (int h = 0; h < 256; h += 8) {
    float4 a0 = *(const float4*)&xr[h], a1 = *(const float4*)&xr[h + 4];
    float4 b0 = *(const float4*)&yr[h], b1 = *(const float4*)&yr[h + 4];
    float e[8];
    e[0] = fmaxf(a0.x + b0.x, 0.f); e[1] = fmaxf(a0.y + b0.y, 0.f);
    e[2] = fmaxf(a0.z + b0.z, 0.f); e[3] = fmaxf(a0.w + b0.w, 0.f);
    e[4] = fmaxf(a1.x + b1.x, 0.f); e[5] = fmaxf(a1.y + b1.y, 0.f);
    e[6] = fmaxf(a1.z + b1.z, 0.f); e[7] = fmaxf(a1.w + b1.w, 0.f);
    #pragma unroll
    for (int q = 0; q < 8; ++q) {
      float4 w = ((const float4*)Wee4g)[h + q];   // uniform -> scalar load
      s.x += e[q] * w.x; s.y += e[q] * w.y;
      s.z += e[q] * w.z; s.w += e[q] * w.w;
    }
  }
  int m = m0 + tm, n = n0 + tn;
  s.x += bee[0]; s.y += bee[1]; s.z += bee[2]; s.w += bee[3];
  ((float4*)out_eel)[m * 256 + n] = s;
  bool edge = (cel[m] > 0.f) && (cel[n] > 0.f) &&
              (s.x > 0.f || s.y > 0.f || s.z > 0.f || s.w > 0.f);
  if (__ballot(edge) != 0ull && (tid & 63) == 0) atomicOr(&anyEdge, 1);
  __syncthreads();
  if (tid == 0 && anyEdge) atomicOr(flags, 1);
}

// ---------------------------------------------------------------------------
__global__ __launch_bounds__(256) void k_zero(float* __restrict__ p) {
  p[blockIdx.x * 256 + threadIdx.x] = 0.f;
}

// ---------------------------------------------------------------------------
// 4) Fused message-passing iteration (bf16 MFMA E-GEMM + masked max-reduce).
// Block tile: 4 m x 16 n = 64 pairs, full k=256; wave w owns k in [w*64,w*64+64).
#define ELP 56
__global__ __launch_bounds__(256) void k_iter(
    const float* __restrict__ Xi, const float* __restrict__ Xj,
    const float* __restrict__ bel, const unsigned short* __restrict__ WeTb,
    const float* __restrict__ Ai, const float* __restrict__ Bj,
    const float* __restrict__ Wt, const float* __restrict__ bne,
    const float* __restrict__ eel, const float* __restrict__ cel,
    float* __restrict__ newcf) {
  __shared__ unsigned short ELs[64 * ELP];     // 64 pairs x 32 h (bf16)
  __shared__ unsigned short WesT[256 * ELP];   // 256 k x 32 h (bf16)
  int tid = threadIdx.x;
  int w = tid >> 6, lane = tid & 63;
  int m0 = (blockIdx.x >> 4) * 4, n0 = (blockIdx.x & 15) * 16;
  f32x4 acc[4][4] = {};

  for (int h0 = 0; h0 < MMH; h0 += 32) {
    { // EL tile: row = pair (4m x 16n), 8 h's per thread
      int row = tid & 63, g = tid >> 6;
      int mI = m0 + (row >> 4), nI = n0 + (row & 15);
      const float4* xip = (const float4*)(Xi + mI * MMH + h0 + g * 8);
      const float4* xjp = (const float4*)(Xj + nI * MMH + h0 + g * 8);
      const float4* bp  = (const float4*)(bel + h0 + g * 8);
      float4 x0 = xip[0], x1 = xip[1];
      float4 y0 = xjp[0], y1 = xjp[1];
      float4 c0 = bp[0],  c1 = bp[1];
      short8 v;
      v[0] = (short)f2bf(fmaxf(x0.x + y0.x + c0.x, 0.f));
      v[1] = (short)f2bf(fmaxf(x0.y + y0.y + c0.y, 0.f));
      v[2] = (short)f2bf(fmaxf(x0.z + y0.z + c0.z, 0.f));
      v[3] = (short)f2bf(fmaxf(x0.w + y0.w + c0.w, 0.f));
      v[4] = (short)f2bf(fmaxf(x1.x + y1.x + c1.x, 0.f));
      v[5] = (short)f2bf(fmaxf(x1.y + y1.y + c1.y, 0.f));
      v[6] = (short)f2bf(fmaxf(x1.z + y1.z + c1.z, 0.f));
      v[7] = (short)f2bf(fmaxf(x1.w + y1.w + c1.w, 0.f));
      *(short8*)&ELs[row * ELP + g * 8] = v;
    }
    { // We tile: contiguous 16KB block, perfectly coalesced
      const unsigned short* WeT = WeTb + (h0 >> 5) * 8192;
      #pragma unroll
      for (int j = 0; j < 4; ++j) {
        int g = tid + 256 * j;
        short8 v = *(const short8*)(WeT + g * 8);
        *(short8*)&WesT[(g >> 2) * ELP + (g & 3) * 8] = v;
      }
    }
    __syncthreads();
    short8 af[4], bf[4];
    #pragma unroll
    for (int rt = 0; rt < 4; ++rt)
      af[rt] = *(const short8*)&ELs[(rt * 16 + (lane & 15)) * ELP + (lane >> 4) * 8];
    #pragma unroll
    for (int ct = 0; ct < 4; ++ct)
      bf[ct] = *(const short8*)&WesT[(w * 64 + ct * 16 + (lane & 15)) * ELP + (lane >> 4) * 8];
    #pragma unroll
    for (int rt = 0; rt < 4; ++rt)
      #pragma unroll
      for (int ct = 0; ct < 4; ++ct)
        acc[rt][ct] = __builtin_amdgcn_mfma_f32_16x16x32_bf16(af[rt], bf[ct], acc[rt][ct], 0, 0, 0);
    __syncthreads();
  }

  // Epilogue: D elem (row = grp*4+r, col = lane&15) of each 16x16 tile.
  int col = lane & 15, grp = lane >> 4;
  #pragma unroll
  for (int rt = 0; rt < 4; ++rt) {
    int m = m0 + rt;
    bool nem = cel[m] > 0.f;
    float4 e4[4]; bool nen[4];
    #pragma unroll
    for (int r = 0; r < 4; ++r) {
      int n = n0 + grp * 4 + r;
      e4[r] = ((const float4*)eel)[m * 256 + n];
      nen[r] = cel[n] > 0.f;
    }
    #pragma unroll
    for (int ct = 0; ct < 4; ++ct) {
      int k = w * 64 + ct * 16 + col;
      float basek = Ai[m * MMH + k] + bne[k];
      float wt0 = Wt[0 * MMH + k], wt1 = Wt[1 * MMH + k];
      float wt2 = Wt[2 * MMH + k], wt3 = Wt[3 * MMH + k];
      float vmax = 0.f;
      #pragma unroll
      for (int r = 0; r < 4; ++r) {
        int n = n0 + grp * 4 + r;
        float base = acc[rt][ct][r] + basek + Bj[n * MMH + k];
        if (nem && nen[r]) {
          if (e4[r].x > 0.f) vmax = fmaxf(vmax, base + e4[r].x * wt0);
          if (e4[r].y > 0.f) vmax = fmaxf(vmax, base + e4[r].y * wt1);
          if (e4[r].z > 0.f) vmax = fmaxf(vmax, base + e4[r].z * wt2);
          if (e4[r].w > 0.f) vmax = fmaxf(vmax, base + e4[r].w * wt3);
        }
      }
      vmax = fmaxf(vmax, __shfl_xor(vmax, 16));
      vmax = fmaxf(vmax, __shfl_xor(vmax, 32));
      if (grp == 0 && vmax > 0.f)
        atomicMax((unsigned int*)&newcf[m * MMH + k], __float_as_uint(vmax));
    }
  }
}

// ---------------------------------------------------------------------------
// 5) cf_{i+1} = has_edge ? newcf : cf_i ; also re-zero newcf for next iter.
__global__ __launch_bounds__(256) void k_select(
    const int* __restrict__ flags, float* __restrict__ newcf,
    float* __restrict__ cat, int iter) {
  int idx = blockIdx.x * 256 + threadIdx.x;
  int m = idx >> 8, k = idx & 255;
  float prev = cat[m * 768 + iter * 256 + k];
  float v = flags[0] ? newcf[idx] : prev;
  cat[m * 768 + (iter + 1) * 256 + k] = v;
  newcf[idx] = 0.f;
}

// ---------------------------------------------------------------------------
extern "C" void kernel_launch(void* const* d_in, const int* in_sizes, int n_in,
                              void* d_out, int out_size, void* d_ws, size_t ws_size,
                              hipStream_t stream) {
  const float* pf   = (const float*)d_in[0];
  const float* Wp   = (const float*)d_in[1];
  const float* bp   = (const float*)d_in[2];
  const float* Wex  = (const float*)d_in[3];
  const float* bex  = (const float*)d_in[4];
  const float* Wel  = (const float*)d_in[5];
  const float* bel  = (const float*)d_in[6];
  const float* Wee  = (const float*)d_in[7];
  const float* bee  = (const float*)d_in[8];
  const float* Wne  = (const float*)d_in[9];
  const float* bne  = (const float*)d_in[10];
  const float* Wch  = (const float*)d_in[11];
  const float* bch  = (const float*)d_in[12];
  const float* Wsem = (const float*)d_in[13];
  const float* bsem = (const float*)d_in[14];
  const float* Wch2 = (const float*)d_in[15];
  const float* bch2 = (const float*)d_in[16];
  float* out = (float*)d_out;
  float* ws  = (float*)d_ws;

  // workspace layout (floats)
  float* cat    = ws;               // 256 x 768 (cf0|cf1|cf2)
  float* Xi     = ws + 196608;
  float* Xj     = Xi + 65536;
  float* Ai     = Xj + 65536;
  float* Bj     = Ai + 65536;
  float* newcf  = Bj + 65536;
  float* hidden = newcf + 65536;
  float* cel    = hidden + 65536;   // 256
  int*   flags  = (int*)(cel + 256);
  float* Wee4g  = cel + 512;        // 256 x 4
  unsigned short* WeTb = (unsigned short*)(Wee4g + 1024);  // 2 x 65536 bf16

  float* out_cf  = out;             // (1,256,256)
  float* out_sem = out + 65536;     // (1,256,40)
  float* out_ex  = out + 75776;     // (1,256,1)
  float* out_eel = out + 76032;     // (1,256,256,4)

  dim3 b16(16, 16);
  k_parent<<<256, 256, 0, stream>>>(pf, Wp, bp, cat);
  k_cel<<<256, 64, 0, stream>>>(cat, Wex, bex, cel, out_ex, flags);
  k_tr<<<dim3(8, 8, 2), dim3(32, 8), 0, stream>>>(Wne, Wee, WeTb, Wee4g);
  k_gemm16<<<dim3(16, 16, 2), b16, 0, stream>>>(cat, 768, Wel, Wel + 65536, 256,
                                                nullptr, Xi, Xj, 256, 256, 256, 0);
  k_edge<<<256, 256, 0, stream>>>(Xi, Xj, bel, Wee4g, bee, cel, out_eel, flags);
  k_zero<<<256, 256, 0, stream>>>(newcf);
  for (int i = 0; i < 2; ++i) {
    const float* cfi = cat + i * 256;                         // lda = 768
    const float* Wi  = Wne + (size_t)(i * 772 + 0)   * 256;
    const float* Wj  = Wne + (size_t)(i * 772 + 256) * 256;
    const float* Wt  = Wne + (size_t)(i * 772 + 768) * 256;
    const float* bnei = bne + i * 256;
    k_gemm16<<<dim3(16, 16, 2), b16, 0, stream>>>(cfi, 768, Wi, Wj, 256,
                                                  nullptr, Ai, Bj, 256, 256, 256, 0);
    k_iter<<<1024, 256, 0, stream>>>(Xi, Xj, bel, WeTb + i * 65536,
                                     Ai, Bj, Wt, bnei, out_eel, cel, newcf);
    k_select<<<256, 256, 0, stream>>>(flags, newcf, cat, i);
  }
  k_gemm16<<<dim3(16, 16, 1), b16, 0, stream>>>(cat, 768, Wch, nullptr, 256, bch,
                                                hidden, nullptr, 256, 256, 768, 1);
  k_gemm16<<<dim3(3, 16, 1), b16, 0, stream>>>(hidden, 256, Wsem, nullptr, 40, bsem,
                                               out_sem, nullptr, 40, NSEMN, 256, 0);
  k_gemm16<<<dim3(16, 16, 1), b16, 0, stream>>>(hidden, 256, Wch2, nullptr, 256, bch2,
                                                out_cf, nullptr, 256, 256, 256, 1);
}